// Round 1
// baseline (77.583 us; speedup 1.0000x reference)
//
#include <hip/hip_runtime.h>
#include <math.h>

// ChADALINE: out[b,o] = sigmoid( (sum_i x[b,i]*W[i,o] + sum_i bias[i,o]) / IN )
// Choquet integral w/ cardinality measure == arithmetic mean; sort eliminated.
//
// R4: single fused kernel, ZERO workspace use. The previous two-phase design
// serialized with a 41 us harness poison-fill of the 256 MiB workspace
// (top-5 rocprof dispatches were all fillBufferAligned @ 262144 KB WRITE_SIZE).
// fp32->bf16 conversion is done inline in registers; MFMA fragment layouts
// identical to the verified R3 kernel (A: row=lane&15, k=quad*8+j;
// B: col=lane&15, k=quad*8+j; C/D: col=lane&15, row=quad*4+reg).
// Grid 1024 blocks (16 mt x 64 nt), 4 waves/block, split-K-4 (256 K each),
// LDS reduce + per-block bias colsum + sigmoid epilogue.

#define BATCH   256
#define IN_DIM  1024
#define OUT_DIM 1024

typedef __bf16 bf16x8 __attribute__((ext_vector_type(8)));
typedef float  f32x4  __attribute__((ext_vector_type(4)));

__global__ __launch_bounds__(256) void chad_fused(
    const float* __restrict__ x,     // [BATCH, IN_DIM]
    const float* __restrict__ w,     // [IN_DIM, OUT_DIM]
    const float* __restrict__ bias,  // [IN_DIM, OUT_DIM]
    float* __restrict__ out)         // [BATCH, OUT_DIM]
{
    __shared__ float red[4][64][4];   // [wave][lane][reg] split-K partials
    __shared__ float bsum[16][16];    // [rowgroup][col] bias colsum partials

    const int t    = threadIdx.x;
    const int lane = t & 63;
    const int wv   = t >> 6;                 // split-K segment
    const int l16  = lane & 15;
    const int quad = lane >> 4;
    const int mt   = blockIdx.x >> 6;        // 0..15 row tile
    const int nt   = blockIdx.x & 63;        // 0..63 col tile

    // --- GEMM: wave wv covers k in [wv*256, wv*256+256), 8 MFMA steps of K=32.
    // A frag j = x[mt*16 + (lane&15)][kbase + quad*8 + j]  (two float4 loads)
    // B frag j = w[kbase + quad*8 + j][nt*16 + (lane&15)]  (8 strided scalars;
    //            lanes 0..15 cover a contiguous 64 B row segment)
    const float* ap = x + (size_t)(mt * 16 + l16) * IN_DIM + wv * 256 + quad * 8;
    const float* bp = w + (size_t)(wv * 256 + quad * 8) * OUT_DIM + nt * 16 + l16;

    f32x4 acc = {0.f, 0.f, 0.f, 0.f};
    #pragma unroll
    for (int i = 0; i < 8; ++i) {
        const float4 a0 = *(const float4*)(ap + i * 32);
        const float4 a1 = *(const float4*)(ap + i * 32 + 4);
        const float* bpi = bp + (size_t)i * 32 * OUT_DIM;
        float bv[8];
        #pragma unroll
        for (int j = 0; j < 8; ++j) bv[j] = bpi[(size_t)j * OUT_DIM];
        bf16x8 af, bfv;
        af[0] = (__bf16)a0.x; af[1] = (__bf16)a0.y;
        af[2] = (__bf16)a0.z; af[3] = (__bf16)a0.w;
        af[4] = (__bf16)a1.x; af[5] = (__bf16)a1.y;
        af[6] = (__bf16)a1.z; af[7] = (__bf16)a1.w;
        #pragma unroll
        for (int j = 0; j < 8; ++j) bfv[j] = (__bf16)bv[j];
        acc = __builtin_amdgcn_mfma_f32_16x16x32_bf16(af, bfv, acc, 0, 0, 0);
    }
    *(f32x4*)&red[wv][lane][0] = acc;

    // --- bias colsum partials: thread t sums 64 rows of col (nt*16 + t&15).
    // Placed after the GEMM so its loads issue behind the fragment loads.
    {
        const int rg = t >> 4;               // 0..15
        const float* bb = bias + (size_t)rg * 64 * OUT_DIM + nt * 16 + (t & 15);
        float s = 0.f;
        #pragma unroll 8
        for (int r = 0; r < 64; ++r) s += bb[(size_t)r * OUT_DIM];
        bsum[rg][t & 15] = s;
    }
    __syncthreads();

    // --- epilogue: thread t -> (row = t>>4, col = t&15) of the 16x16 tile.
    // C/D layout: value (row,col) lives in lane (row>>2)*16+col, reg row&3.
    const int row = t >> 4, col = t & 15;
    const int rl  = ((row >> 2) << 4) + col;
    const int rr  = row & 3;
    float v = red[0][rl][rr] + red[1][rl][rr] + red[2][rl][rr] + red[3][rl][rr];
    float cs = 0.f;
    #pragma unroll
    for (int p = 0; p < 16; ++p) cs += bsum[p][col];   // same-addr per 16 lanes: LDS broadcast
    v = (v + cs) * (1.0f / (float)IN_DIM);
    out[(size_t)(mt * 16 + row) * OUT_DIM + nt * 16 + col] = 1.0f / (1.0f + __expf(-v));
}

extern "C" void kernel_launch(void* const* d_in, const int* in_sizes, int n_in,
                              void* d_out, int out_size, void* d_ws, size_t ws_size,
                              hipStream_t stream) {
    const float* x  = (const float*)d_in[0];
    const float* w  = (const float*)d_in[1];
    const float* b  = (const float*)d_in[2];
    chad_fused<<<(BATCH / 16) * (OUT_DIM / 16), 256, 0, stream>>>(
        x, w, b, (float*)d_out);
}

// Round 2
// 69.215 us; speedup vs baseline: 1.1209x; 1.1209x over previous
//
#include <hip/hip_runtime.h>
#include <math.h>

// ChADALINE: out[b,o] = sigmoid( (sum_i x[b,i]*W[i,o] + sum_i bias[i,o]) / IN )
// Choquet integral w/ cardinality measure == arithmetic mean; sort eliminated.
//
// R5: fused AND coalesced. R4 regressed because it re-read W per mt-block with
// per-lane strided scalar loads (262K load instrs). R5 is a classic LDS-staged
// GEMM: 32x32 tile/block, grid 256 (1 block/CU, nt=bid&31 -> blocks sharing a
// W/bias slice land on the same XCD L2). FULL K=1024 staged in LDS as bf16
// (A[32][1032] + B[32][1032] transposed = 129 KiB, gfx950 has 160 KiB/CU), so
// the kernel has exactly 2 barriers and every global load is a coalesced
// float4. Bias colsum runs in fp32 through the same coalesced stream pass
// (16 independent iters, LDS-scratch tree reduce) - no serial latency chain.
// MFMA fragment layouts identical to verified R3/R4 (A: row=lane&15,
// k=quad*8+j; B: col=lane&15, k=quad*8+j; C/D: col=lane&15, row=quad*4+reg).

#define BATCH   256
#define IN_DIM  1024
#define OUT_DIM 1024

#define BM 32
#define BN 32
#define KP (IN_DIM + 8)   // padded LDS row stride in bf16 elems (mult of 8 ->
                          // 16B-aligned rows; 516 dwords = even b128 bank spread)

typedef __bf16 bf16x4 __attribute__((ext_vector_type(4)));
typedef __bf16 bf16x8 __attribute__((ext_vector_type(8)));
typedef float  f32x4  __attribute__((ext_vector_type(4)));

__global__ __launch_bounds__(256) void chad_fused(
    const float* __restrict__ x,     // [BATCH, IN_DIM]
    const float* __restrict__ w,     // [IN_DIM, OUT_DIM]
    const float* __restrict__ bias,  // [IN_DIM, OUT_DIM]
    float* __restrict__ out)         // [BATCH, OUT_DIM]
{
    __shared__ __bf16 Alds[BM][KP];  // x rows, [row][k]
    __shared__ __bf16 Blds[BN][KP];  // W cols, [col][k] (transposed at write)
    __shared__ float  bscr[32][32];  // bias colsum partials [k-group][col]
    __shared__ float  csum[BN];

    const int t    = threadIdx.x;
    const int lane = t & 63;
    const int wv   = t >> 6;
    const int l16  = lane & 15;
    const int quad = lane >> 4;
    const int mt   = blockIdx.x >> 5;   // 0..7  (row tile)
    const int nt   = blockIdx.x & 31;   // 0..31 (col tile; bid%8 = nt%8 -> XCD-local slice reuse)

    // ---- stage A: x[mt*32 + it][t*4 .. t*4+3] -> Alds[it][t*4..], bf16.
    // Per wave-instr: 64 lanes x 16 B contiguous = perfectly coalesced.
    {
        const float* xs = x + (size_t)(mt * BM) * IN_DIM + t * 4;
        #pragma unroll 4
        for (int it = 0; it < 32; ++it) {
            const float4 v = *(const float4*)(xs + (size_t)it * IN_DIM);
            bf16x4 o = { (__bf16)v.x, (__bf16)v.y, (__bf16)v.z, (__bf16)v.w };
            *(bf16x4*)&Alds[it][t * 4] = o;
        }
    }

    // ---- stage B (W, transposed to [col][k]) + bias colsum partials.
    // Thread t owns cols c..c+3, even row kb; loads rows kb,kb+1 (float4 x2),
    // packs (k,k+1) bf16 pairs -> u32 ds_write (4-way bank conflict max).
    {
        const int kb = 2 * (t >> 3);          // 0,2,..,62 within 64-row group
        const int c  = 4 * (t & 7);           // 0,4,..,28
        const float* wsrc = w    + (size_t)kb * OUT_DIM + nt * BN + c;
        const float* bsrc = bias + (size_t)kb * OUT_DIM + nt * BN + c;
        f32x4 bacc = {0.f, 0.f, 0.f, 0.f};
        #pragma unroll 4
        for (int it = 0; it < 16; ++it) {
            const size_t roff = (size_t)it * 64 * OUT_DIM;
            const float4 w0 = *(const float4*)(wsrc + roff);
            const float4 w1 = *(const float4*)(wsrc + roff + OUT_DIM);
            const float4 b0 = *(const float4*)(bsrc + roff);
            const float4 b1 = *(const float4*)(bsrc + roff + OUT_DIM);
            const int k = it * 64 + kb;
            #pragma unroll
            for (int i = 0; i < 4; ++i) {
                union { __bf16 h[2]; unsigned int u; } p;
                p.h[0] = (__bf16)((&w0.x)[i]);
                p.h[1] = (__bf16)((&w1.x)[i]);
                *(unsigned int*)&Blds[c + i][k] = p.u;
            }
            bacc[0] += b0.x + b1.x;
            bacc[1] += b0.y + b1.y;
            bacc[2] += b0.z + b1.z;
            bacc[3] += b0.w + b1.w;
        }
        *(f32x4*)&bscr[t >> 3][c] = bacc;
    }
    __syncthreads();

    // ---- bias colsum finalize (wave 0 front, overlaps others' MFMA issue)
    if (t < BN) {
        float s = 0.f;
        #pragma unroll
        for (int g = 0; g < 32; ++g) s += bscr[g][t];
        csum[t] = s;
    }

    // ---- MFMA: wave quadrant (wr,wc) = (wv>>1, wv&1), 16x16 out, K=1024.
    const __bf16* ab = &Alds[(wv >> 1) * 16 + l16][quad * 8];
    const __bf16* bb = &Blds[(wv &  1) * 16 + l16][quad * 8];
    f32x4 acc = {0.f, 0.f, 0.f, 0.f};
    #pragma unroll
    for (int s = 0; s < 32; ++s) {
        const bf16x8 af = *(const bf16x8*)(ab + s * 32);
        const bf16x8 bf = *(const bf16x8*)(bb + s * 32);
        acc = __builtin_amdgcn_mfma_f32_16x16x32_bf16(af, bf, acc, 0, 0, 0);
    }
    __syncthreads();   // csum ready

    // ---- epilogue: lane holds rows quad*4+r, col l16 of its 16x16 tile.
    const float cs   = csum[(wv & 1) * 16 + l16];
    const int  orow0 = mt * BM + (wv >> 1) * 16 + quad * 4;
    const int  ocol  = nt * BN + (wv &  1) * 16 + l16;
    float* op = out + (size_t)orow0 * OUT_DIM + ocol;
    #pragma unroll
    for (int r = 0; r < 4; ++r) {
        const float v = (acc[r] + cs) * (1.0f / (float)IN_DIM);
        op[(size_t)r * OUT_DIM] = 1.0f / (1.0f + __expf(-v));
    }
}

extern "C" void kernel_launch(void* const* d_in, const int* in_sizes, int n_in,
                              void* d_out, int out_size, void* d_ws, size_t ws_size,
                              hipStream_t stream) {
    const float* x  = (const float*)d_in[0];
    const float* w  = (const float*)d_in[1];
    const float* b  = (const float*)d_in[2];
    chad_fused<<<(BATCH / BM) * (OUT_DIM / BN), 256, 0, stream>>>(
        x, w, b, (float*)d_out);
}

// Round 3
// 67.635 us; speedup vs baseline: 1.1471x; 1.0234x over previous
//
#include <hip/hip_runtime.h>
#include <math.h>

// ChADALINE: out[b,o] = sigmoid( (sum_i x[b,i]*W[i,o] + sum_i bias[i,o]) / IN )
// Choquet integral w/ cardinality measure == arithmetic mean; sort eliminated.
//
// R6: R5 structure (fused, full-K LDS staging, 2 barriers) but 512 threads =
// 8 waves = 2 waves/SIMD. R5 ran 4 waves (1/SIMD) with 129 KiB LDS: every
// issue slot and dependent-latency cycle was exposed. Per-thread work halved:
// 48 float4 loads (was 96), A-stage uses ds_write_b128 (8 writes, was 16),
// MFMA is split-K-2 per 16x16 quadrant (waves 0-3 K-low, 4-7 K-high) with an
// LDS f32x4 reduce in the epilogue. LDS 145 KiB, 2 barriers, grid 256 =
// 1 block/CU, nt = bid&31 keeps W/bias slices XCD-local.
// Fragment layouts unchanged (verified R3-R5): A row=lane&15, k=quad*8+j;
// B col=lane&15, k=quad*8+j; C/D col=lane&15, row=quad*4+reg.

#define BATCH   256
#define IN_DIM  1024
#define OUT_DIM 1024

#define BM 32
#define BN 32
#define KP (IN_DIM + 8)   // padded LDS row stride (bf16): 16B-aligned rows

typedef __bf16 bf16x8 __attribute__((ext_vector_type(8)));
typedef float  f32x4  __attribute__((ext_vector_type(4)));

__global__ __launch_bounds__(512) void chad_fused(
    const float* __restrict__ x,     // [BATCH, IN_DIM]
    const float* __restrict__ w,     // [IN_DIM, OUT_DIM]
    const float* __restrict__ bias,  // [IN_DIM, OUT_DIM]
    float* __restrict__ out)         // [BATCH, OUT_DIM]
{
    __shared__ __bf16 Alds[BM][KP];   // x rows   [row][k]      66.0 KB
    __shared__ __bf16 Blds[BN][KP];   // W cols   [col][k]      66.0 KB
    __shared__ float  bscr[64][32];   // bias partials           8.0 KB
    __shared__ float  red[8][64][4];  // split-K partials        8.0 KB
    __shared__ float  csum[BN];

    const int t    = threadIdx.x;
    const int lane = t & 63;
    const int wv   = t >> 6;            // 0..7
    const int l16  = lane & 15;
    const int quad = lane >> 4;
    const int mt   = blockIdx.x >> 5;   // 0..7  row tile
    const int nt   = blockIdx.x & 31;   // 0..31 col tile (bid%8 = nt%8 -> XCD-local W/bias)

    // ---- stage A: thread t owns row t>>4, 8 chunks of 8 elems.
    // Loads: 2x float4 per chunk (coalesced 16B/lane); write ds_write_b128.
    {
        const int ar = t >> 4;                 // 0..31
        const int ac = (t & 15) * 8;           // 0..120
        const float* xs = x + (size_t)(mt * BM + ar) * IN_DIM + ac;
        #pragma unroll 2
        for (int it = 0; it < 8; ++it) {
            const float4 v0 = *(const float4*)(xs + it * 128);
            const float4 v1 = *(const float4*)(xs + it * 128 + 4);
            bf16x8 o;
            o[0] = (__bf16)v0.x; o[1] = (__bf16)v0.y;
            o[2] = (__bf16)v0.z; o[3] = (__bf16)v0.w;
            o[4] = (__bf16)v1.x; o[5] = (__bf16)v1.y;
            o[6] = (__bf16)v1.z; o[7] = (__bf16)v1.w;
            *(bf16x8*)&Alds[ar][ac + it * 128] = o;
        }
    }

    // ---- stage B (W transposed to [col][k]) + bias colsum partials.
    // Thread t: cols c..c+3, row-pair (kb,kb+1), 8 iters stepping 128 rows.
    // Pack (k,k+1) bf16 pairs -> u32 ds_write.
    {
        const int kb = 2 * (t >> 3);           // 0,2,..,126
        const int c  = 4 * (t & 7);            // 0,4,..,28
        const float* wsrc = w    + (size_t)kb * OUT_DIM + nt * BN + c;
        const float* bsrc = bias + (size_t)kb * OUT_DIM + nt * BN + c;
        f32x4 bacc = {0.f, 0.f, 0.f, 0.f};
        #pragma unroll 2
        for (int it = 0; it < 8; ++it) {
            const size_t roff = (size_t)it * 128 * OUT_DIM;
            const float4 w0 = *(const float4*)(wsrc + roff);
            const float4 w1 = *(const float4*)(wsrc + roff + OUT_DIM);
            const float4 b0 = *(const float4*)(bsrc + roff);
            const float4 b1 = *(const float4*)(bsrc + roff + OUT_DIM);
            const int k = kb + it * 128;
            #pragma unroll
            for (int i = 0; i < 4; ++i) {
                union { __bf16 h[2]; unsigned int u; } p;
                p.h[0] = (__bf16)((&w0.x)[i]);
                p.h[1] = (__bf16)((&w1.x)[i]);
                *(unsigned int*)&Blds[c + i][k] = p.u;
            }
            bacc[0] += b0.x + b1.x;
            bacc[1] += b0.y + b1.y;
            bacc[2] += b0.z + b1.z;
            bacc[3] += b0.w + b1.w;
        }
        *(f32x4*)&bscr[t >> 3][c] = bacc;
    }
    __syncthreads();

    // ---- bias colsum finalize (first 32 threads; overlaps others' MFMA)
    if (t < BN) {
        float s = 0.f;
        #pragma unroll
        for (int g = 0; g < 64; ++g) s += bscr[g][t];
        csum[t] = s;
    }

    // ---- MFMA: wave wv -> quadrant (qr,qc) = ((wv>>1)&1, wv&1), K-half wv>>2.
    {
        const int qr = (wv >> 1) & 1, qc = wv & 1, kh = wv >> 2;
        const __bf16* ab = &Alds[qr * 16 + l16][kh * 512 + quad * 8];
        const __bf16* bb = &Blds[qc * 16 + l16][kh * 512 + quad * 8];
        f32x4 acc = {0.f, 0.f, 0.f, 0.f};
        #pragma unroll
        for (int s = 0; s < 16; ++s) {
            const bf16x8 af = *(const bf16x8*)(ab + s * 32);
            const bf16x8 bf = *(const bf16x8*)(bb + s * 32);
            acc = __builtin_amdgcn_mfma_f32_16x16x32_bf16(af, bf, acc, 0, 0, 0);
        }
        *(f32x4*)&red[wv][lane][0] = acc;
    }
    __syncthreads();

    // ---- epilogue: thread t -> row r = t>>4 (0..31), cols (t&15), (t&15)+16.
    // Within quadrant q: value (r&15, c&15) lives at lane ((r&15)>>2)*16+(c&15),
    // reg (r&3); combine K-halves q and q+4.
    {
        const int r = t >> 4;
        float* op = out + (size_t)(mt * BM + r) * OUT_DIM + nt * BN;
        #pragma unroll
        for (int h = 0; h < 2; ++h) {
            const int c  = (t & 15) + h * 16;
            const int q  = ((r >> 4) << 1) + (c >> 4);
            const int rl = (((r & 15) >> 2) << 4) + (c & 15);
            const int rr = r & 3;
            float v = red[q][rl][rr] + red[q + 4][rl][rr];
            v = (v + csum[c]) * (1.0f / (float)IN_DIM);
            op[c] = 1.0f / (1.0f + __expf(-v));
        }
    }
}

extern "C" void kernel_launch(void* const* d_in, const int* in_sizes, int n_in,
                              void* d_out, int out_size, void* d_ws, size_t ws_size,
                              hipStream_t stream) {
    const float* x  = (const float*)d_in[0];
    const float* w  = (const float*)d_in[1];
    const float* b  = (const float*)d_in[2];
    chad_fused<<<(BATCH / BM) * (OUT_DIM / BN), 512, 0, stream>>>(
        x, w, b, (float*)d_out);
}